// Round 17
// baseline (797.174 us; speedup 1.0000x reference)
//
#include <hip/hip_runtime.h>
#include <math.h>

#define N_NODES 50000
#define N_EDGES 800000
#define FEAT    16
#define HID     64
#define KORD    32
#define NCLS    8

// W[d,k,f,c] flat index = (d*KORD + k)*80*64 + f*64 + c ; only rows f<16 matter (H0==0).
#define WSL     5120   // 80*64, per-(d,k) slice stride in floats
#define SLOT    (N_NODES * FEAT)   // 800000 elements per slab slot
#define CSR_CAP (N_EDGES + 4 * N_NODES + 16)   // padded-segment capacity

typedef __attribute__((ext_vector_type(8))) short bf8_t;   // 8 bf16 (4 VGPRs)
typedef __attribute__((ext_vector_type(4))) float f32x4;

static constexpr size_t Aln(size_t x) { return (x + 255) & ~size_t(255); }

// ---- workspace layout (bytes), total ~220 MB ----
static constexpr size_t OFF_DEGPO   = 0;                                      // 8 x N ints (zeroed)
static constexpr size_t OFF_DEGPI   = OFF_DEGPO + Aln((size_t)8 * N_NODES * 4);
static constexpr size_t OFF_CUR_DST = OFF_DEGPI + Aln((size_t)8 * N_NODES * 4);
static constexpr size_t OFF_CUR_SRC = OFF_CUR_DST + Aln(N_NODES * 4);
static constexpr size_t ZERO_BYTES  = OFF_CUR_SRC + Aln(N_NODES * 4);   // zero [0, ZERO_BYTES)
static constexpr size_t OFF_DEG_OUT = ZERO_BYTES;
static constexpr size_t OFF_DEG_IN  = OFF_DEG_OUT + Aln(N_NODES * 4);
static constexpr size_t OFF_OFF_DST = OFF_DEG_IN + Aln((N_NODES + 1) * 4);
static constexpr size_t OFF_OFF_SRC = OFF_OFF_DST + Aln((N_NODES + 1) * 4);
static constexpr size_t OFF_CSRD    = OFF_OFF_SRC + Aln((N_NODES + 1) * 4);  // uint{deg:16|idx:16}
static constexpr size_t OFF_CSRS    = OFF_CSRD + Aln((size_t)CSR_CAP * 4);
static constexpr size_t OFF_SLAB    = OFF_CSRS + Aln((size_t)CSR_CAP * 4);   // 64 f32 slots (dir*32+k)
static constexpr size_t OFF_BSZH    = OFF_SLAB + Aln((size_t)64 * SLOT * 4);
static constexpr size_t OFF_BSZL    = OFF_BSZH + Aln((size_t)32 * 8 * 64 * 8 * 2);
static constexpr size_t WS_TOTAL    = OFF_BSZL + Aln((size_t)32 * 8 * 64 * 8 * 2);

__device__ __forceinline__ ushort f2bf(float v) {   // f32 -> bf16 (RNE)
    unsigned int b = __float_as_uint(v);
    b += 0x7FFFu + ((b >> 16) & 1u);
    return (ushort)(b >> 16);
}
__device__ __forceinline__ float bf2f(ushort h) {
    return __uint_as_float((unsigned int)h << 16);
}

// XCD-private histograms: copy = blockIdx.x & 7 (matches round-robin XCD dispatch),
// so every atomic lands in the local L2 (no cross-die line ping-pong).
__global__ void count_deg_kernel(const int* __restrict__ ei,
                                 int* __restrict__ privO, int* __restrict__ privI) {
    int e4 = blockIdx.x * blockDim.x + threadIdx.x;   // 4 edges per thread
    if (e4 * 4 >= N_EDGES) return;
    const int c = (blockIdx.x & 7) * N_NODES;
    int4 s = *(const int4*)&ei[e4 * 4];
    int4 d = *(const int4*)&ei[N_EDGES + e4 * 4];
    atomicAdd(&privO[c + s.x], 1); atomicAdd(&privO[c + s.y], 1);
    atomicAdd(&privO[c + s.z], 1); atomicAdd(&privO[c + s.w], 1);
    atomicAdd(&privI[c + d.x], 1); atomicAdd(&privI[c + d.y], 1);
    atomicAdd(&privI[c + d.z], 1); atomicAdd(&privI[c + d.w], 1);
}

__global__ void reduce_deg_kernel(const int* __restrict__ privO, const int* __restrict__ privI,
                                  int* __restrict__ deg_out, int* __restrict__ deg_in) {
    int i = blockIdx.x * blockDim.x + threadIdx.x;
    if (i >= N_NODES) return;
    int so = 0, si = 0;
    #pragma unroll
    for (int c = 0; c < 8; ++c) {
        so += privO[c * N_NODES + i];
        si += privI[c * N_NODES + i];
    }
    deg_out[i] = so;
    deg_in[i] = si;
}

// two exclusive scans over PADDED degrees (pdeg = deg rounded up to multiple of 4,
// so every CSR segment start is 16B-aligned for uint4 loads).
// block 0: degA->offA, block 1: degB->offB
__global__ __launch_bounds__(1024) void scan_kernel(const int* __restrict__ degA, int* __restrict__ offA,
                                                    const int* __restrict__ degB, int* __restrict__ offB) {
    const int* deg = blockIdx.x ? degB : degA;
    int* off = blockIdx.x ? offB : offA;
    __shared__ int wsum[16];
    __shared__ int s_run;
    const int t = threadIdx.x, lane = t & 63, wid = t >> 6;
    if (t == 0) s_run = 0;
    __syncthreads();
    for (int base = 0; base < N_NODES; base += 1024) {
        int i = base + t;
        int v = (i < N_NODES) ? ((deg[i] + 3) & ~3) : 0;   // padded
        int xv = v;
        #pragma unroll
        for (int d = 1; d < 64; d <<= 1) {
            int tt = __shfl_up(xv, d, 64);
            if (lane >= d) xv += tt;
        }
        if (lane == 63) wsum[wid] = xv;
        __syncthreads();
        int add = s_run;
        for (int w = 0; w < wid; ++w) add += wsum[w];
        if (i < N_NODES) off[i] = add + xv - v;   // exclusive (padded)
        __syncthreads();
        if (t == 1023) s_run = add + xv;
        __syncthreads();
    }
    if (t == 0) off[N_NODES] = s_run;
}

// combined fill (R15-proven): entries land in [off, off+deg) of each padded segment.
__global__ void fill_csr_kernel(const int* __restrict__ ei,
                                const int* __restrict__ deg_out, const int* __restrict__ deg_in,
                                const int* __restrict__ off_dst, const int* __restrict__ off_src,
                                int* __restrict__ cur_dst, int* __restrict__ cur_src,
                                unsigned int* __restrict__ csrd, unsigned int* __restrict__ csrs) {
    int e = blockIdx.x * blockDim.x + threadIdx.x;
    if (e >= N_EDGES) return;
    int s = ei[e], d = ei[N_EDGES + e];
    int p = off_dst[d] + atomicAdd(&cur_dst[d], 1);
    csrd[p] = ((unsigned int)deg_out[s] << 16) | (unsigned int)s;  // w = 1/deg_out[src]
    int q = off_src[s] + atomicAdd(&cur_src[s], 1);
    csrs[q] = ((unsigned int)deg_in[d] << 16) | (unsigned int)d;   // w = 1/deg_in[dst]
}

// gather v4: 16-lane node group; quad u handles 4 CONSECUTIVE edges e0+4u..e0+4u+3.
// The quad's 4 fq-lanes load the SAME 16B uint4 (1 coalesced request vs 16 scalar);
// per-lane: 1 csr VMEM + 4 row VMEM per 16-edge iteration (vs 4+4 before).
// Segment start `beg` is 16B-aligned (padded scan); masked tail via `end`.
__device__ __forceinline__ float4 gather4v(const unsigned int* __restrict__ csr, int beg, int end,
                                           int u, int fq, const float* __restrict__ src) {
    float4 acc = {0.f, 0.f, 0.f, 0.f};
    for (int e0 = beg; e0 < end; e0 += 16) {
        const int eb = e0 + 4 * u;
        uint4 q = *(const uint4*)&csr[eb];   // in-bounds: CSR_CAP slack covers overshoot
        unsigned int pk0 = (eb < end)     ? q.x : 0x10000u;
        unsigned int pk1 = (eb + 1 < end) ? q.y : 0x10000u;
        unsigned int pk2 = (eb + 2 < end) ? q.z : 0x10000u;
        unsigned int pk3 = (eb + 3 < end) ? q.w : 0x10000u;
        float w0 = (eb < end)     ? 1.0f / (float)(pk0 >> 16) : 0.0f;  // exact IEEE div
        float w1 = (eb + 1 < end) ? 1.0f / (float)(pk1 >> 16) : 0.0f;
        float w2 = (eb + 2 < end) ? 1.0f / (float)(pk2 >> 16) : 0.0f;
        float w3 = (eb + 3 < end) ? 1.0f / (float)(pk3 >> 16) : 0.0f;
        const float4 r0 = *(const float4*)&src[(pk0 & 0xFFFFu) * FEAT + fq * 4];
        const float4 r1 = *(const float4*)&src[(pk1 & 0xFFFFu) * FEAT + fq * 4];
        const float4 r2 = *(const float4*)&src[(pk2 & 0xFFFFu) * FEAT + fq * 4];
        const float4 r3 = *(const float4*)&src[(pk3 & 0xFFFFu) * FEAT + fq * 4];
        acc.x += w0 * r0.x + w1 * r1.x + w2 * r2.x + w3 * r3.x;
        acc.y += w0 * r0.y + w1 * r1.y + w2 * r2.y + w3 * r3.y;
        acc.z += w0 * r0.z + w1 * r1.z + w2 * r2.z + w3 * r3.z;
        acc.w += w0 * r0.w + w1 * r1.w + w2 * r2.w + w3 * r3.w;
    }
    return acc;
}

__device__ __forceinline__ float4 reduce_u(float4 a) {
    a.x += __shfl_xor(a.x, 4); a.y += __shfl_xor(a.y, 4);
    a.z += __shfl_xor(a.z, 4); a.w += __shfl_xor(a.w, 4);
    a.x += __shfl_xor(a.x, 8); a.y += __shfl_xor(a.y, 8);
    a.z += __shfl_xor(a.z, 8); a.w += __shfl_xor(a.w, 8);
    return a;
}

// k=0,1. XCD-parity dir split: dir = blockIdx.x & 1 (R10-proven).
__global__ __launch_bounds__(256) void init_kernel(
    const float* __restrict__ x,
    const int* __restrict__ off_dst, const unsigned int* __restrict__ csrd,
    const int* __restrict__ off_src, const unsigned int* __restrict__ csrs,
    const int* __restrict__ deg_out, const int* __restrict__ deg_in,
    float* __restrict__ slab) {
    const int dir = blockIdx.x & 1;
    const int bi  = blockIdx.x >> 1;
    const int* off = dir ? off_src : off_dst;
    const unsigned int* csr = dir ? csrs : csrd;
    const int* dga = dir ? deg_out : deg_in;   // by-dst list length = in-degree, by-src = out-degree
    const int t = threadIdx.x;
    const int g = t >> 4, l = t & 15, u = l >> 2, fq = l & 3;
    const int i = bi * 16 + g;
    const int b = off[i], e = b + dga[i];
    float4 a = reduce_u(gather4v(csr, b, e, u, fq, x));
    if (u == 0) {
        const int ro = i * FEAT + fq * 4;
        float4 xr = *(const float4*)&x[ro];
        *(float4*)&slab[(size_t)(dir * 32 + 0) * SLOT + ro] = xr;
        *(float4*)&slab[(size_t)(dir * 32 + 1) * SLOT + ro] = a;
    }
}

// Chebyshev step k: slab[dir*32+k] = 2*P*slab[k-1] - slab[k-2]. (R10/R12-proven shape)
__global__ __launch_bounds__(256) void step_kernel(
    const int* __restrict__ off_dst, const unsigned int* __restrict__ csrd,
    const int* __restrict__ off_src, const unsigned int* __restrict__ csrs,
    const int* __restrict__ deg_out, const int* __restrict__ deg_in,
    float* __restrict__ slab, int k) {
    const int dir = blockIdx.x & 1;
    const int bi  = blockIdx.x >> 1;
    const int* off = dir ? off_src : off_dst;
    const unsigned int* csr = dir ? csrs : csrd;
    const int* dga = dir ? deg_out : deg_in;
    const float* prev = slab + (size_t)(dir * 32 + k - 1) * SLOT;
    const float* pp   = slab + (size_t)(dir * 32 + k - 2) * SLOT;
    float*       outp = slab + (size_t)(dir * 32 + k) * SLOT;
    const int t = threadIdx.x;
    const int g = t >> 4, l = t & 15, u = l >> 2, fq = l & 3;
    const int i = bi * 16 + g;
    const int b = off[i], e = b + dga[i];
    float4 a = reduce_u(gather4v(csr, b, e, u, fq, prev));
    if (u == 0) {
        const int ro = i * FEAT + fq * 4;
        float4 p = *(const float4*)&pp[ro];
        float4 t2;
        t2.x = 2.f * a.x - p.x; t2.y = 2.f * a.y - p.y;
        t2.z = 2.f * a.z - p.z; t2.w = 2.f * a.w - p.w;
        *(float4*)&outp[ro] = t2;
    }
}

// Build MFMA-swizzled bf16 hi/lo weight fragments.
// Fragment element (kc, nc, lane l, i): si = kc*2 + ((l>>4)>>1); f = ((l>>4)&1)*8 + i;
// c = nc*16 + (l&15); value = W[d=si>>5][kz=si&31][f][c] (c<64 -> Wz, else Wh col c-64).
__global__ void wswiz_kernel(const float* __restrict__ Wz, const float* __restrict__ Wh,
                             ushort* __restrict__ bszh, ushort* __restrict__ bszl) {
    int idx = blockIdx.x * blockDim.x + threadIdx.x;   // 32*8*64 = 16384 threads
    if (idx >= 32 * 8 * 64) return;
    int l  = idx & 63;
    int nc = (idx >> 6) & 7;
    int kc = idx >> 9;
    int si = kc * 2 + ((l >> 4) >> 1);
    int f0 = ((l >> 4) & 1) * 8;
    int c  = nc * 16 + (l & 15);
    const float* W = (c < 64) ? Wz : Wh;
    int cc = (c < 64) ? c : c - 64;
    ushort vh[8], vl[8];
    #pragma unroll
    for (int i = 0; i < 8; ++i) {
        float v = W[(size_t)si * WSL + (f0 + i) * 64 + cc];
        ushort h = f2bf(v);
        vh[i] = h;
        vl[i] = f2bf(v - bf2f(h));
    }
    ushort* dh = &bszh[(size_t)idx * 8];
    *(ushort4*)dh       = make_ushort4(vh[0], vh[1], vh[2], vh[3]);
    *(ushort4*)(dh + 4) = make_ushort4(vh[4], vh[5], vh[6], vh[7]);
    ushort* dl = &bszl[(size_t)idx * 8];
    *(ushort4*)dl       = make_ushort4(vl[0], vl[1], vl[2], vl[3]);
    *(ushort4*)(dl + 4) = make_ushort4(vl[4], vl[5], vl[6], vl[7]);
}

__device__ __forceinline__ void cvtA(const float* __restrict__ ap, bf8_t& aHi, bf8_t& aLo) {
    float4 a0 = *(const float4*)ap;
    float4 a1 = *(const float4*)(ap + 4);
    float av[8] = {a0.x, a0.y, a0.z, a0.w, a1.x, a1.y, a1.z, a1.w};
    #pragma unroll
    for (int i = 0; i < 8; ++i) {
        ushort h = f2bf(av[i]);
        aHi[i] = (short)h;
        aLo[i] = (short)f2bf(av[i] - bf2f(h));
    }
}

// Fused readout v5 (R15-proven): block = 8 waves x 16 nodes = 128 nodes, 512 threads.
// One 16 KB B-frag set staged per block per kc (double-buffered), shared by 8 waves.
__global__ __launch_bounds__(512) void final_kernel(
    const float* __restrict__ slab, const ushort* __restrict__ bszh, const ushort* __restrict__ bszl,
    const float* __restrict__ bz, const float* __restrict__ bh,
    const float* __restrict__ lin_w, const float* __restrict__ lin_b,
    float* __restrict__ out) {
    __shared__ alignas(16) ushort sfrag[2][8192];   // [buf][hi 4096 | lo 4096] ushorts = 16 KB/buf
    const int t = threadIdx.x;
    const int w = t >> 6, l = t & 63;
    const int cl = l & 15, hi = l >> 4;
    const int n0 = blockIdx.x * 128 + w * 16;
    const int nodeA = n0 + cl;
    const bool ok = nodeA < N_NODES;
    const int siAdd = hi >> 1, f0 = (hi & 1) * 8;

    f32x4 acc[8];
    #pragma unroll
    for (int nc = 0; nc < 8; ++nc) {
        int c = nc * 16 + cl;
        float bias = (c < 64) ? bz[c] : bh[c - 64];
        acc[nc] = (f32x4){bias, bias, bias, bias};
    }

    // stage kc=0: 512 threads x 2 uint4 = 16 KB
    {
        const uint4* sH = (const uint4*)(bszh);
        const uint4* sL = (const uint4*)(bszl);
        uint4* d = (uint4*)sfrag[0];
        d[t] = sH[t];
        d[t + 512] = sL[t];
    }
    __syncthreads();

    for (int kc = 0; kc < 32; ++kc) {
        const int buf = kc & 1;
        if (kc < 31) {   // prefetch next kc's frags into the other buffer
            const uint4* sH = (const uint4*)(bszh + (size_t)(kc + 1) * 4096);
            const uint4* sL = (const uint4*)(bszl + (size_t)(kc + 1) * 4096);
            uint4* d = (uint4*)sfrag[buf ^ 1];
            d[t] = sH[t];
            d[t + 512] = sL[t];
        }
        bf8_t aH = (bf8_t)0, aL = (bf8_t)0;
        if (ok) {
            int si = kc * 2 + siAdd;
            cvtA(&slab[(size_t)si * SLOT + nodeA * FEAT + f0], aH, aL);
        }
        const ushort* fb = sfrag[buf];
        #pragma unroll
        for (int nc = 0; nc < 8; ++nc) {
            bf8_t bHi = *(const bf8_t*)&fb[nc * 512 + l * 8];
            bf8_t bLo = *(const bf8_t*)&fb[4096 + nc * 512 + l * 8];
            acc[nc] = __builtin_amdgcn_mfma_f32_16x16x32_bf16(aH, bHi, acc[nc], 0, 0, 0);
            acc[nc] = __builtin_amdgcn_mfma_f32_16x16x32_bf16(aL, bHi, acc[nc], 0, 0, 0);
            acc[nc] = __builtin_amdgcn_mfma_f32_16x16x32_bf16(aH, bLo, acc[nc], 0, 0, 0);
        }
        __syncthreads();
    }

    // epilogue: acc[nc][i] = H at node n0 + hi*4 + i, col nc*16+cl (nc<4: Hz, nc>=4: Hh)
    float po[4][8];
    #pragma unroll
    for (int i = 0; i < 4; ++i)
        #pragma unroll
        for (int cls = 0; cls < 8; ++cls) po[i][cls] = 0.f;
    #pragma unroll
    for (int i = 0; i < 4; ++i) {
        #pragma unroll
        for (int nc = 0; nc < 4; ++nc) {
            float hz = acc[nc][i], hh = acc[nc + 4][i];
            float z  = 1.f / (1.f + __expf(-hz));
            float ht = tanhf(hh);
            float v  = fmaxf(0.f, (1.f - z) * ht);
            const float* lwr = &lin_w[(nc * 16 + cl) * 8];
            #pragma unroll
            for (int cls = 0; cls < 8; ++cls) po[i][cls] += v * lwr[cls];
        }
    }
    #pragma unroll
    for (int m = 1; m < 16; m <<= 1) {
        #pragma unroll
        for (int i = 0; i < 4; ++i)
            #pragma unroll
            for (int cls = 0; cls < 8; ++cls)
                po[i][cls] += __shfl_xor(po[i][cls], m, 16);
    }
    if (cl < 8) {
        #pragma unroll
        for (int i = 0; i < 4; ++i) {
            int node = n0 + hi * 4 + i;
            if (node < N_NODES) out[node * NCLS + cl] = po[i][cl] + lin_b[cl];
        }
    }
}

extern "C" void kernel_launch(void* const* d_in, const int* in_sizes, int n_in,
                              void* d_out, int out_size, void* d_ws, size_t ws_size,
                              hipStream_t stream) {
    const float* x   = (const float*)d_in[0];
    const int*   ei  = (const int*)d_in[1];
    const float* Wz  = (const float*)d_in[2];
    const float* bz  = (const float*)d_in[3];
    // d_in[4] = W_r, d_in[5] = b_r : unused (H0 == 0 makes R irrelevant)
    const float* Wh  = (const float*)d_in[6];
    const float* bh  = (const float*)d_in[7];
    const float* lw  = (const float*)d_in[8];
    const float* lb  = (const float*)d_in[9];
    float* out = (float*)d_out;
    char* ws = (char*)d_ws;

    int*  privO   = (int*)(ws + OFF_DEGPO);
    int*  privI   = (int*)(ws + OFF_DEGPI);
    int*  cur_dst = (int*)(ws + OFF_CUR_DST);
    int*  cur_src = (int*)(ws + OFF_CUR_SRC);
    int*  deg_out = (int*)(ws + OFF_DEG_OUT);
    int*  deg_in  = (int*)(ws + OFF_DEG_IN);
    int*  off_dst = (int*)(ws + OFF_OFF_DST);
    int*  off_src = (int*)(ws + OFF_OFF_SRC);
    unsigned int* csrd = (unsigned int*)(ws + OFF_CSRD);
    unsigned int* csrs = (unsigned int*)(ws + OFF_CSRS);
    float*  slab = (float*)(ws + OFF_SLAB);
    ushort* bszh = (ushort*)(ws + OFF_BSZH);
    ushort* bszl = (ushort*)(ws + OFF_BSZL);

    hipMemsetAsync(ws, 0, ZERO_BYTES, stream);

    const int EB = (N_EDGES + 255) / 256;       // 3125
    const int NB16 = N_NODES / 16;              // 3125 (exact)
    count_deg_kernel<<<(N_EDGES / 4 + 255) / 256, 256, 0, stream>>>(ei, privO, privI);
    reduce_deg_kernel<<<(N_NODES + 255) / 256, 256, 0, stream>>>(privO, privI, deg_out, deg_in);
    scan_kernel<<<2, 1024, 0, stream>>>(deg_in, off_dst, deg_out, off_src);
    fill_csr_kernel<<<EB, 256, 0, stream>>>(ei, deg_out, deg_in, off_dst, off_src,
                                            cur_dst, cur_src, csrd, csrs);
    wswiz_kernel<<<(32 * 8 * 64 + 255) / 256, 256, 0, stream>>>(Wz, Wh, bszh, bszl);
    init_kernel<<<NB16 * 2, 256, 0, stream>>>(x, off_dst, csrd, off_src, csrs,
                                              deg_out, deg_in, slab);

    for (int k = 2; k < KORD; ++k)
        step_kernel<<<NB16 * 2, 256, 0, stream>>>(off_dst, csrd, off_src, csrs,
                                                  deg_out, deg_in, slab, k);

    final_kernel<<<(N_NODES + 127) / 128, 512, 0, stream>>>(slab, bszh, bszl,
                                                            bz, bh, lw, lb, out);
}

// Round 18
// 778.488 us; speedup vs baseline: 1.0240x; 1.0240x over previous
//
#include <hip/hip_runtime.h>
#include <math.h>

#define N_NODES 50000
#define N_EDGES 800000
#define FEAT    16
#define HID     64
#define KORD    32
#define NCLS    8

// W[d,k,f,c] flat index = (d*KORD + k)*80*64 + f*64 + c ; only rows f<16 matter (H0==0).
#define WSL     5120   // 80*64, per-(d,k) slice stride in floats
#define SLOT    (N_NODES * FEAT)   // 800000 elements per slab slot

typedef __attribute__((ext_vector_type(8))) short bf8_t;   // 8 bf16 (4 VGPRs)
typedef __attribute__((ext_vector_type(4))) float f32x4;

static constexpr size_t Aln(size_t x) { return (x + 255) & ~size_t(255); }

// ---- workspace layout (bytes), total ~213 MB ----
static constexpr size_t OFF_DEG_OUT = 0;
static constexpr size_t OFF_DEG_IN  = OFF_DEG_OUT + Aln(N_NODES * 4);
static constexpr size_t OFF_CUR_DST = OFF_DEG_IN  + Aln(N_NODES * 4);
static constexpr size_t OFF_CUR_SRC = OFF_CUR_DST + Aln(N_NODES * 4);
static constexpr size_t ZERO_BYTES  = OFF_CUR_SRC + Aln(N_NODES * 4);   // zero [0, ZERO_BYTES)
static constexpr size_t OFF_OFF_DST = ZERO_BYTES;
static constexpr size_t OFF_OFF_SRC = OFF_OFF_DST + Aln((N_NODES + 1) * 4);
static constexpr size_t OFF_CSRD    = OFF_OFF_SRC + Aln((N_NODES + 1) * 4);  // uint{deg:16|idx:16}
static constexpr size_t OFF_CSRS    = OFF_CSRD + Aln(N_EDGES * 4);
static constexpr size_t OFF_SLAB    = OFF_CSRS + Aln(N_EDGES * 4);           // 64 f32 slots (dir*32+k)
static constexpr size_t OFF_BSZH    = OFF_SLAB + Aln((size_t)64 * SLOT * 4);
static constexpr size_t OFF_BSZL    = OFF_BSZH + Aln((size_t)32 * 8 * 64 * 8 * 2);
static constexpr size_t WS_TOTAL    = OFF_BSZL + Aln((size_t)32 * 8 * 64 * 8 * 2);

__device__ __forceinline__ ushort f2bf(float v) {   // f32 -> bf16 (RNE)
    unsigned int b = __float_as_uint(v);
    b += 0x7FFFu + ((b >> 16) & 1u);
    return (ushort)(b >> 16);
}
__device__ __forceinline__ float bf2f(ushort h) {
    return __uint_as_float((unsigned int)h << 16);
}

// XCD-parity split (R16-proven +): even blocks count deg_out, odd count deg_in ->
// each 200 KB counter array takes atomics from only 4 XCDs (less cross-L2 ping-pong).
__global__ void count_deg_kernel(const int* __restrict__ ei,
                                 int* __restrict__ deg_out, int* __restrict__ deg_in) {
    const int half = blockIdx.x & 1;
    int e4 = (blockIdx.x >> 1) * blockDim.x + threadIdx.x;   // 4 edges per thread
    if (e4 * 4 >= N_EDGES) return;
    if (half == 0) {
        int4 s = *(const int4*)&ei[e4 * 4];
        atomicAdd(&deg_out[s.x], 1); atomicAdd(&deg_out[s.y], 1);
        atomicAdd(&deg_out[s.z], 1); atomicAdd(&deg_out[s.w], 1);
    } else {
        int4 d = *(const int4*)&ei[N_EDGES + e4 * 4];
        atomicAdd(&deg_in[d.x], 1);  atomicAdd(&deg_in[d.y], 1);
        atomicAdd(&deg_in[d.z], 1);  atomicAdd(&deg_in[d.w], 1);
    }
}

// two exclusive scans (one block each): block 0: degA->offA, block 1: degB->offB
__global__ __launch_bounds__(1024) void scan_kernel(const int* __restrict__ degA, int* __restrict__ offA,
                                                    const int* __restrict__ degB, int* __restrict__ offB) {
    const int* deg = blockIdx.x ? degB : degA;
    int* off = blockIdx.x ? offB : offA;
    __shared__ int wsum[16];
    __shared__ int s_run;
    const int t = threadIdx.x, lane = t & 63, wid = t >> 6;
    if (t == 0) s_run = 0;
    __syncthreads();
    for (int base = 0; base < N_NODES; base += 1024) {
        int i = base + t;
        int v = (i < N_NODES) ? deg[i] : 0;
        int xv = v;
        #pragma unroll
        for (int d = 1; d < 64; d <<= 1) {
            int tt = __shfl_up(xv, d, 64);
            if (lane >= d) xv += tt;
        }
        if (lane == 63) wsum[wid] = xv;
        __syncthreads();
        int add = s_run;
        for (int w = 0; w < wid; ++w) add += wsum[w];
        if (i < N_NODES) off[i] = add + xv - v;   // exclusive
        __syncthreads();
        if (t == 1023) s_run = add + xv;
        __syncthreads();
    }
    if (t == 0) off[N_NODES] = s_run;
}

// combined fill (R15-proven: parity split of this kernel HURT, keep combined)
__global__ void fill_csr_kernel(const int* __restrict__ ei,
                                const int* __restrict__ deg_out, const int* __restrict__ deg_in,
                                const int* __restrict__ off_dst, const int* __restrict__ off_src,
                                int* __restrict__ cur_dst, int* __restrict__ cur_src,
                                unsigned int* __restrict__ csrd, unsigned int* __restrict__ csrs) {
    int e = blockIdx.x * blockDim.x + threadIdx.x;
    if (e >= N_EDGES) return;
    int s = ei[e], d = ei[N_EDGES + e];
    // packed entry: {deg:16 | idx:16}; weight computed in-gather as exact 1.0f/deg
    int p = off_dst[d] + atomicAdd(&cur_dst[d], 1);
    csrd[p] = ((unsigned int)deg_out[s] << 16) | (unsigned int)s;  // w = 1/deg_out[src]
    int q = off_src[s] + atomicAdd(&cur_src[s], 1);
    csrs[q] = ((unsigned int)deg_in[d] << 16) | (unsigned int)d;   // w = 1/deg_in[dst]
}

// gather (R4/R7/R12/R15-proven): 16-lane node group, lane = (u=edge 0..3, fq=chunk 0..3).
__device__ __forceinline__ float4 gather4d(const unsigned int* __restrict__ csr, int beg, int end,
                                           int u, int fq, const float* __restrict__ src) {
    float4 acc = {0.f, 0.f, 0.f, 0.f};
    for (int e0 = beg; e0 < end; e0 += 16) {
        int ea = e0 + u, eb = e0 + 4 + u, ec = e0 + 8 + u, ed = e0 + 12 + u;
        unsigned int pa = (ea < end) ? csr[ea] : 0x10000u;   // pad: deg=1, idx=0
        unsigned int pb = (eb < end) ? csr[eb] : 0x10000u;
        unsigned int pc = (ec < end) ? csr[ec] : 0x10000u;
        unsigned int pd = (ed < end) ? csr[ed] : 0x10000u;
        float wa = (ea < end) ? 1.0f / (float)(pa >> 16) : 0.0f;  // exact IEEE div, matches ref
        float wb = (eb < end) ? 1.0f / (float)(pb >> 16) : 0.0f;
        float wc = (ec < end) ? 1.0f / (float)(pc >> 16) : 0.0f;
        float wd = (ed < end) ? 1.0f / (float)(pd >> 16) : 0.0f;
        const float4 ra = *(const float4*)&src[(pa & 0xFFFFu) * FEAT + fq * 4];
        const float4 rb = *(const float4*)&src[(pb & 0xFFFFu) * FEAT + fq * 4];
        const float4 rc = *(const float4*)&src[(pc & 0xFFFFu) * FEAT + fq * 4];
        const float4 rd = *(const float4*)&src[(pd & 0xFFFFu) * FEAT + fq * 4];
        acc.x += wa * ra.x + wb * rb.x + wc * rc.x + wd * rd.x;
        acc.y += wa * ra.y + wb * rb.y + wc * rc.y + wd * rd.y;
        acc.z += wa * ra.z + wb * rb.z + wc * rc.z + wd * rd.z;
        acc.w += wa * ra.w + wb * rb.w + wc * rc.w + wd * rd.w;
    }
    return acc;
}

__device__ __forceinline__ float4 reduce_u(float4 a) {
    a.x += __shfl_xor(a.x, 4); a.y += __shfl_xor(a.y, 4);
    a.z += __shfl_xor(a.z, 4); a.w += __shfl_xor(a.w, 4);
    a.x += __shfl_xor(a.x, 8); a.y += __shfl_xor(a.y, 8);
    a.z += __shfl_xor(a.z, 8); a.w += __shfl_xor(a.w, 8);
    return a;
}

// k=0,1. XCD-parity dir split: dir = blockIdx.x & 1 (R10-proven).
__global__ __launch_bounds__(256) void init_kernel(
    const float* __restrict__ x,
    const int* __restrict__ off_dst, const unsigned int* __restrict__ csrd,
    const int* __restrict__ off_src, const unsigned int* __restrict__ csrs,
    float* __restrict__ slab) {
    const int dir = blockIdx.x & 1;
    const int bi  = blockIdx.x >> 1;
    const int* off = dir ? off_src : off_dst;
    const unsigned int* csr = dir ? csrs : csrd;
    const int t = threadIdx.x;
    const int g = t >> 4, l = t & 15, u = l >> 2, fq = l & 3;
    const int i = bi * 16 + g;
    const int b = off[i], e = off[i + 1];
    float4 a = reduce_u(gather4d(csr, b, e, u, fq, x));
    if (u == 0) {
        const int ro = i * FEAT + fq * 4;
        float4 xr = *(const float4*)&x[ro];
        *(float4*)&slab[(size_t)(dir * 32 + 0) * SLOT + ro] = xr;
        *(float4*)&slab[(size_t)(dir * 32 + 1) * SLOT + ro] = a;
    }
}

// Chebyshev step k: slab[dir*32+k] = 2*P*slab[k-1] - slab[k-2]. (R10/R12/R15-proven)
__global__ __launch_bounds__(256) void step_kernel(
    const int* __restrict__ off_dst, const unsigned int* __restrict__ csrd,
    const int* __restrict__ off_src, const unsigned int* __restrict__ csrs,
    float* __restrict__ slab, int k) {
    const int dir = blockIdx.x & 1;
    const int bi  = blockIdx.x >> 1;
    const int* off = dir ? off_src : off_dst;
    const unsigned int* csr = dir ? csrs : csrd;
    const float* prev = slab + (size_t)(dir * 32 + k - 1) * SLOT;
    const float* pp   = slab + (size_t)(dir * 32 + k - 2) * SLOT;
    float*       outp = slab + (size_t)(dir * 32 + k) * SLOT;
    const int t = threadIdx.x;
    const int g = t >> 4, l = t & 15, u = l >> 2, fq = l & 3;
    const int i = bi * 16 + g;
    const int b = off[i], e = off[i + 1];
    float4 a = reduce_u(gather4d(csr, b, e, u, fq, prev));
    if (u == 0) {
        const int ro = i * FEAT + fq * 4;
        float4 p = *(const float4*)&pp[ro];
        float4 t2;
        t2.x = 2.f * a.x - p.x; t2.y = 2.f * a.y - p.y;
        t2.z = 2.f * a.z - p.z; t2.w = 2.f * a.w - p.w;
        *(float4*)&outp[ro] = t2;
    }
}

// Build MFMA-swizzled bf16 hi/lo weight fragments.
// Fragment element (kc, nc, lane l, i): si = kc*2 + ((l>>4)>>1); f = ((l>>4)&1)*8 + i;
// c = nc*16 + (l&15); value = W[d=si>>5][kz=si&31][f][c] (c<64 -> Wz, else Wh col c-64).
__global__ void wswiz_kernel(const float* __restrict__ Wz, const float* __restrict__ Wh,
                             ushort* __restrict__ bszh, ushort* __restrict__ bszl) {
    int idx = blockIdx.x * blockDim.x + threadIdx.x;   // 32*8*64 = 16384 threads
    if (idx >= 32 * 8 * 64) return;
    int l  = idx & 63;
    int nc = (idx >> 6) & 7;
    int kc = idx >> 9;
    int si = kc * 2 + ((l >> 4) >> 1);
    int f0 = ((l >> 4) & 1) * 8;
    int c  = nc * 16 + (l & 15);
    const float* W = (c < 64) ? Wz : Wh;
    int cc = (c < 64) ? c : c - 64;
    ushort vh[8], vl[8];
    #pragma unroll
    for (int i = 0; i < 8; ++i) {
        float v = W[(size_t)si * WSL + (f0 + i) * 64 + cc];
        ushort h = f2bf(v);
        vh[i] = h;
        vl[i] = f2bf(v - bf2f(h));
    }
    ushort* dh = &bszh[(size_t)idx * 8];
    *(ushort4*)dh       = make_ushort4(vh[0], vh[1], vh[2], vh[3]);
    *(ushort4*)(dh + 4) = make_ushort4(vh[4], vh[5], vh[6], vh[7]);
    ushort* dl = &bszl[(size_t)idx * 8];
    *(ushort4*)dl       = make_ushort4(vl[0], vl[1], vl[2], vl[3]);
    *(ushort4*)(dl + 4) = make_ushort4(vl[4], vl[5], vl[6], vl[7]);
}

__device__ __forceinline__ void cvtA(const float* __restrict__ ap, bf8_t& aHi, bf8_t& aLo) {
    float4 a0 = *(const float4*)ap;
    float4 a1 = *(const float4*)(ap + 4);
    float av[8] = {a0.x, a0.y, a0.z, a0.w, a1.x, a1.y, a1.z, a1.w};
    #pragma unroll
    for (int i = 0; i < 8; ++i) {
        ushort h = f2bf(av[i]);
        aHi[i] = (short)h;
        aLo[i] = (short)f2bf(av[i] - bf2f(h));
    }
}

// Fused readout v5 (R15-proven): block = 8 waves x 16 nodes = 128 nodes, 512 threads.
// One 16 KB B-frag set staged per block per kc (double-buffered), shared by 8 waves.
__global__ __launch_bounds__(512) void final_kernel(
    const float* __restrict__ slab, const ushort* __restrict__ bszh, const ushort* __restrict__ bszl,
    const float* __restrict__ bz, const float* __restrict__ bh,
    const float* __restrict__ lin_w, const float* __restrict__ lin_b,
    float* __restrict__ out) {
    __shared__ alignas(16) ushort sfrag[2][8192];   // [buf][hi 4096 | lo 4096] ushorts = 16 KB/buf
    const int t = threadIdx.x;
    const int w = t >> 6, l = t & 63;
    const int cl = l & 15, hi = l >> 4;
    const int n0 = blockIdx.x * 128 + w * 16;
    const int nodeA = n0 + cl;
    const bool ok = nodeA < N_NODES;
    const int siAdd = hi >> 1, f0 = (hi & 1) * 8;

    f32x4 acc[8];
    #pragma unroll
    for (int nc = 0; nc < 8; ++nc) {
        int c = nc * 16 + cl;
        float bias = (c < 64) ? bz[c] : bh[c - 64];
        acc[nc] = (f32x4){bias, bias, bias, bias};
    }

    // stage kc=0: 512 threads x 2 uint4 = 16 KB
    {
        const uint4* sH = (const uint4*)(bszh);
        const uint4* sL = (const uint4*)(bszl);
        uint4* d = (uint4*)sfrag[0];
        d[t] = sH[t];
        d[t + 512] = sL[t];
    }
    __syncthreads();

    for (int kc = 0; kc < 32; ++kc) {
        const int buf = kc & 1;
        if (kc < 31) {   // prefetch next kc's frags into the other buffer
            const uint4* sH = (const uint4*)(bszh + (size_t)(kc + 1) * 4096);
            const uint4* sL = (const uint4*)(bszl + (size_t)(kc + 1) * 4096);
            uint4* d = (uint4*)sfrag[buf ^ 1];
            d[t] = sH[t];
            d[t + 512] = sL[t];
        }
        bf8_t aH = (bf8_t)0, aL = (bf8_t)0;
        if (ok) {
            int si = kc * 2 + siAdd;
            cvtA(&slab[(size_t)si * SLOT + nodeA * FEAT + f0], aH, aL);
        }
        const ushort* fb = sfrag[buf];
        #pragma unroll
        for (int nc = 0; nc < 8; ++nc) {
            bf8_t bHi = *(const bf8_t*)&fb[nc * 512 + l * 8];
            bf8_t bLo = *(const bf8_t*)&fb[4096 + nc * 512 + l * 8];
            acc[nc] = __builtin_amdgcn_mfma_f32_16x16x32_bf16(aH, bHi, acc[nc], 0, 0, 0);
            acc[nc] = __builtin_amdgcn_mfma_f32_16x16x32_bf16(aL, bHi, acc[nc], 0, 0, 0);
            acc[nc] = __builtin_amdgcn_mfma_f32_16x16x32_bf16(aH, bLo, acc[nc], 0, 0, 0);
        }
        __syncthreads();
    }

    // epilogue: acc[nc][i] = H at node n0 + hi*4 + i, col nc*16+cl (nc<4: Hz, nc>=4: Hh)
    float po[4][8];
    #pragma unroll
    for (int i = 0; i < 4; ++i)
        #pragma unroll
        for (int cls = 0; cls < 8; ++cls) po[i][cls] = 0.f;
    #pragma unroll
    for (int i = 0; i < 4; ++i) {
        #pragma unroll
        for (int nc = 0; nc < 4; ++nc) {
            float hz = acc[nc][i], hh = acc[nc + 4][i];
            float z  = 1.f / (1.f + __expf(-hz));
            float ht = tanhf(hh);
            float v  = fmaxf(0.f, (1.f - z) * ht);
            const float* lwr = &lin_w[(nc * 16 + cl) * 8];
            #pragma unroll
            for (int cls = 0; cls < 8; ++cls) po[i][cls] += v * lwr[cls];
        }
    }
    #pragma unroll
    for (int m = 1; m < 16; m <<= 1) {
        #pragma unroll
        for (int i = 0; i < 4; ++i)
            #pragma unroll
            for (int cls = 0; cls < 8; ++cls)
                po[i][cls] += __shfl_xor(po[i][cls], m, 16);
    }
    if (cl < 8) {
        #pragma unroll
        for (int i = 0; i < 4; ++i) {
            int node = n0 + hi * 4 + i;
            if (node < N_NODES) out[node * NCLS + cl] = po[i][cl] + lin_b[cl];
        }
    }
}

extern "C" void kernel_launch(void* const* d_in, const int* in_sizes, int n_in,
                              void* d_out, int out_size, void* d_ws, size_t ws_size,
                              hipStream_t stream) {
    const float* x   = (const float*)d_in[0];
    const int*   ei  = (const int*)d_in[1];
    const float* Wz  = (const float*)d_in[2];
    const float* bz  = (const float*)d_in[3];
    // d_in[4] = W_r, d_in[5] = b_r : unused (H0 == 0 makes R irrelevant)
    const float* Wh  = (const float*)d_in[6];
    const float* bh  = (const float*)d_in[7];
    const float* lw  = (const float*)d_in[8];
    const float* lb  = (const float*)d_in[9];
    float* out = (float*)d_out;
    char* ws = (char*)d_ws;

    int*  deg_out = (int*)(ws + OFF_DEG_OUT);
    int*  deg_in  = (int*)(ws + OFF_DEG_IN);
    int*  cur_dst = (int*)(ws + OFF_CUR_DST);
    int*  cur_src = (int*)(ws + OFF_CUR_SRC);
    int*  off_dst = (int*)(ws + OFF_OFF_DST);
    int*  off_src = (int*)(ws + OFF_OFF_SRC);
    unsigned int* csrd = (unsigned int*)(ws + OFF_CSRD);
    unsigned int* csrs = (unsigned int*)(ws + OFF_CSRS);
    float*  slab = (float*)(ws + OFF_SLAB);
    ushort* bszh = (ushort*)(ws + OFF_BSZH);
    ushort* bszl = (ushort*)(ws + OFF_BSZL);

    hipMemsetAsync(ws, 0, ZERO_BYTES, stream);

    const int EB = (N_EDGES + 255) / 256;       // 3125
    const int NB16 = N_NODES / 16;              // 3125 (exact)
    count_deg_kernel<<<(N_EDGES / 4 + 255) / 256 * 2, 256, 0, stream>>>(ei, deg_out, deg_in);
    scan_kernel<<<2, 1024, 0, stream>>>(deg_in, off_dst, deg_out, off_src);
    fill_csr_kernel<<<EB, 256, 0, stream>>>(ei, deg_out, deg_in, off_dst, off_src,
                                            cur_dst, cur_src, csrd, csrs);
    wswiz_kernel<<<(32 * 8 * 64 + 255) / 256, 256, 0, stream>>>(Wz, Wh, bszh, bszl);
    init_kernel<<<NB16 * 2, 256, 0, stream>>>(x, off_dst, csrd, off_src, csrs, slab);

    for (int k = 2; k < KORD; ++k)
        step_kernel<<<NB16 * 2, 256, 0, stream>>>(off_dst, csrd, off_src, csrs, slab, k);

    final_kernel<<<(N_NODES + 127) / 128, 512, 0, stream>>>(slab, bszh, bszl,
                                                            bz, bh, lw, lb, out);
}